// Round 1
// baseline (142.686 us; speedup 1.0000x reference)
//
#include <hip/hip_runtime.h>

// Pointer-generator final distribution.
// out[b,v] = p_gen[b] * vocab_dist[b,v]  (+ scatter of (1-p_gen)*attn via src_ids)
// p_gen[b] = sigmoid(ctx[b].w_c + state[b].w_s + emb[b].w_y + bias)
//
// One block per batch row. Memory-bound: ~137.6 MB total traffic.

#define BLK 256

__global__ __launch_bounds__(BLK) void pg_fused_kernel(
    const float* __restrict__ vocab_dist,   // [B,V]
    const float* __restrict__ attn_dist,    // [B,T]
    const float* __restrict__ context,      // [B,ENC]
    const float* __restrict__ state,        // [B,HID]
    const float* __restrict__ emb,          // [B,EMB]
    const int*   __restrict__ src_ids,      // [B,T]
    const int*   __restrict__ vocab_size_p, // [1]
    const float* __restrict__ w_c,          // [ENC]
    const float* __restrict__ w_s,          // [HID]
    const float* __restrict__ w_y,          // [EMB]
    const float* __restrict__ bias,         // [1]
    float* __restrict__ out,                // [B,V]
    int T, int V, int ENC, int HID, int EMB)
{
    const int row = blockIdx.x;
    const int tid = threadIdx.x;

    // ---- 1. partial dot products (float4 vectorized; dims are /4) ----
    float acc = 0.f;
    {
        const float4* a4 = (const float4*)(context + (size_t)row * ENC);
        const float4* w4 = (const float4*)w_c;
        for (int i = tid; i < (ENC >> 2); i += BLK) {
            float4 a = a4[i], w = w4[i];
            acc += a.x * w.x + a.y * w.y + a.z * w.z + a.w * w.w;
        }
    }
    {
        const float4* a4 = (const float4*)(state + (size_t)row * HID);
        const float4* w4 = (const float4*)w_s;
        for (int i = tid; i < (HID >> 2); i += BLK) {
            float4 a = a4[i], w = w4[i];
            acc += a.x * w.x + a.y * w.y + a.z * w.z + a.w * w.w;
        }
    }
    {
        const float4* a4 = (const float4*)(emb + (size_t)row * EMB);
        const float4* w4 = (const float4*)w_y;
        for (int i = tid; i < (EMB >> 2); i += BLK) {
            float4 a = a4[i], w = w4[i];
            acc += a.x * w.x + a.y * w.y + a.z * w.z + a.w * w.w;
        }
    }

    // ---- 2. reduce 256 lanes -> p_gen (wave=64 shuffle, then LDS) ----
    #pragma unroll
    for (int off = 32; off > 0; off >>= 1)
        acc += __shfl_down(acc, off, 64);

    __shared__ float red[BLK / 64];
    __shared__ float s_pgen;
    if ((tid & 63) == 0) red[tid >> 6] = acc;
    __syncthreads();
    if (tid == 0) {
        float s = red[0] + red[1] + red[2] + red[3] + bias[0];
        s_pgen = 1.f / (1.f + expf(-s));
    }
    __syncthreads();
    const float pg = s_pgen;

    // ---- 3. scale vocab_dist row (the bandwidth carrier) ----
    const size_t rowV = (size_t)row * V;
    const float4* vd4 = (const float4*)(vocab_dist + rowV);
    float4*       o4  = (float4*)(out + rowV);
    const int nv4 = V >> 2;
    for (int i = tid; i < nv4; i += BLK) {
        float4 v = vd4[i];
        v.x *= pg; v.y *= pg; v.z *= pg; v.w *= pg;
        o4[i] = v;
    }
    for (int i = (nv4 << 2) + tid; i < V; i += BLK)   // tail (V%4 != 0)
        out[rowV + i] = vocab_dist[rowV + i] * pg;

    // Barrier drains vmcnt(0): scaled stores for this row have reached this
    // XCD's L2 before any lane of this block issues atomics into the row.
    // Only this block ever touches this row, so no cross-XCD hazard.
    __syncthreads();

    // ---- 4. scatter-add the copy distribution ----
    const int   vs = *vocab_size_p;
    const float pc = 1.f - pg;
    const float* at = attn_dist + (size_t)row * T;
    const int*   si = src_ids  + (size_t)row * T;
    float* orow = out + rowV;
    for (int t = tid; t < T; t += BLK) {
        int id = si[t];
        if (id < vs) atomicAdd(orow + id, pc * at[t]);  // dup ids possible
    }
}

extern "C" void kernel_launch(void* const* d_in, const int* in_sizes, int n_in,
                              void* d_out, int out_size, void* d_ws, size_t ws_size,
                              hipStream_t stream) {
    const float* vocab_dist = (const float*)d_in[0];
    const float* attn_dist  = (const float*)d_in[1];
    const float* context    = (const float*)d_in[2];
    const float* state      = (const float*)d_in[3];
    const float* emb        = (const float*)d_in[4];
    const int*   src_ids    = (const int*)d_in[5];
    const int*   vocab_sz   = (const int*)d_in[6];
    const float* w_c        = (const float*)d_in[7];
    const float* w_s        = (const float*)d_in[8];
    const float* w_y        = (const float*)d_in[9];
    const float* bias       = (const float*)d_in[10];
    float* out = (float*)d_out;

    const int ENC = in_sizes[7];
    const int HID = in_sizes[8];
    const int EMB = in_sizes[9];
    const int B   = in_sizes[2] / ENC;
    const int T   = in_sizes[1] / B;
    const int V   = in_sizes[0] / B;

    pg_fused_kernel<<<B, BLK, 0, stream>>>(
        vocab_dist, attn_dist, context, state, emb, src_ids, vocab_sz,
        w_c, w_s, w_y, bias, out, T, V, ENC, HID, EMB);
}

// Round 2
// 140.179 us; speedup vs baseline: 1.0179x; 1.0179x over previous
//
#include <hip/hip_runtime.h>

// Pointer-generator final distribution.
// out[b,v] = p_gen[b] * vocab_dist[b,v]  (+ scatter of (1-p_gen)*attn via src_ids)
// p_gen[b] = sigmoid(ctx[b].w_c + state[b].w_s + emb[b].w_y + bias)
//
// One block per batch row, 1024 threads (16 waves): 512 blocks -> 2 blocks/CU
// -> 32 waves/CU = full occupancy. R0's 256-thread version sat at 16%
// occupancy / 33% HBM — latency-bound.

#define BLK 1024
#define NWAVE (BLK / 64)

__global__ __launch_bounds__(BLK) void pg_fused_kernel(
    const float* __restrict__ vocab_dist,   // [B,V]
    const float* __restrict__ attn_dist,    // [B,T]
    const float* __restrict__ context,      // [B,ENC]
    const float* __restrict__ state,        // [B,HID]
    const float* __restrict__ emb,          // [B,EMB]
    const int*   __restrict__ src_ids,      // [B,T]
    const int*   __restrict__ vocab_size_p, // [1]
    const float* __restrict__ w_c,          // [ENC]
    const float* __restrict__ w_s,          // [HID]
    const float* __restrict__ w_y,          // [EMB]
    const float* __restrict__ bias,         // [1]
    float* __restrict__ out,                // [B,V]
    int T, int V, int ENC, int HID, int EMB)
{
    const int row = blockIdx.x;
    const int tid = threadIdx.x;

    // ---- 1. partial dot products (float4 vectorized; dims are /4) ----
    float acc = 0.f;
    {
        const float4* a4 = (const float4*)(context + (size_t)row * ENC);
        const float4* w4 = (const float4*)w_c;
        for (int i = tid; i < (ENC >> 2); i += BLK) {
            float4 a = a4[i], w = w4[i];
            acc += a.x * w.x + a.y * w.y + a.z * w.z + a.w * w.w;
        }
    }
    {
        const float4* a4 = (const float4*)(state + (size_t)row * HID);
        const float4* w4 = (const float4*)w_s;
        for (int i = tid; i < (HID >> 2); i += BLK) {
            float4 a = a4[i], w = w4[i];
            acc += a.x * w.x + a.y * w.y + a.z * w.z + a.w * w.w;
        }
    }
    {
        const float4* a4 = (const float4*)(emb + (size_t)row * EMB);
        const float4* w4 = (const float4*)w_y;
        for (int i = tid; i < (EMB >> 2); i += BLK) {
            float4 a = a4[i], w = w4[i];
            acc += a.x * w.x + a.y * w.y + a.z * w.z + a.w * w.w;
        }
    }

    // ---- 2. reduce 1024 lanes -> p_gen (wave=64 shuffle, then LDS) ----
    #pragma unroll
    for (int off = 32; off > 0; off >>= 1)
        acc += __shfl_down(acc, off, 64);

    __shared__ float red[NWAVE];
    __shared__ float s_pgen;
    if ((tid & 63) == 0) red[tid >> 6] = acc;
    __syncthreads();
    if (tid == 0) {
        float s = bias[0];
        #pragma unroll
        for (int w = 0; w < NWAVE; ++w) s += red[w];
        s_pgen = 1.f / (1.f + expf(-s));
    }
    __syncthreads();
    const float pg = s_pgen;

    // ---- 3. scale vocab_dist row (the bandwidth carrier) ----
    const size_t rowV = (size_t)row * V;
    const float4* vd4 = (const float4*)(vocab_dist + rowV);
    float4*       o4  = (float4*)(out + rowV);
    const int nv4 = V >> 2;
    for (int i = tid; i < nv4; i += BLK) {
        float4 v = vd4[i];
        v.x *= pg; v.y *= pg; v.z *= pg; v.w *= pg;
        o4[i] = v;
    }
    for (int i = (nv4 << 2) + tid; i < V; i += BLK)   // tail (V%4 != 0)
        out[rowV + i] = vocab_dist[rowV + i] * pg;

    // Barrier drains vmcnt(0): scaled stores for this row have reached this
    // XCD's L2 before any lane of this block issues atomics into the row.
    // Only this block ever touches this row, so no cross-XCD hazard.
    __syncthreads();

    // ---- 4. scatter-add the copy distribution ----
    const int   vs = *vocab_size_p;
    const float pc = 1.f - pg;
    const float* at = attn_dist + (size_t)row * T;
    const int*   si = src_ids  + (size_t)row * T;
    float* orow = out + rowV;
    for (int t = tid; t < T; t += BLK) {
        int id = si[t];
        if (id < vs) atomicAdd(orow + id, pc * at[t]);  // dup ids possible
    }
}

extern "C" void kernel_launch(void* const* d_in, const int* in_sizes, int n_in,
                              void* d_out, int out_size, void* d_ws, size_t ws_size,
                              hipStream_t stream) {
    const float* vocab_dist = (const float*)d_in[0];
    const float* attn_dist  = (const float*)d_in[1];
    const float* context    = (const float*)d_in[2];
    const float* state      = (const float*)d_in[3];
    const float* emb        = (const float*)d_in[4];
    const int*   src_ids    = (const int*)d_in[5];
    const int*   vocab_sz   = (const int*)d_in[6];
    const float* w_c        = (const float*)d_in[7];
    const float* w_s        = (const float*)d_in[8];
    const float* w_y        = (const float*)d_in[9];
    const float* bias       = (const float*)d_in[10];
    float* out = (float*)d_out;

    const int ENC = in_sizes[7];
    const int HID = in_sizes[8];
    const int EMB = in_sizes[9];
    const int B   = in_sizes[2] / ENC;
    const int T   = in_sizes[1] / B;
    const int V   = in_sizes[0] / B;

    pg_fused_kernel<<<B, BLK, 0, stream>>>(
        vocab_dist, attn_dist, context, state, emb, src_ids, vocab_sz,
        w_c, w_s, w_y, bias, out, T, V, ENC, HID, EMB);
}